// Round 11
// baseline (163.353 us; speedup 1.0000x reference)
//
#include <hip/hip_runtime.h>

// B=4, L=S=2048, H=8, E=D=64.  KM[bh][t][e] = sum_s K[b,s,h,e]*M[s,t] (split
// bf16 hi/lo), then flash attention z = Q*KM/8, causal, online softmax.
// Round 11: round-10 pipeline + last-finisher in-kernel merge of kv-half
// partials (device-scope atomic flag per (bh,kk); second finisher merges,
// overlapped with attn tail) — drops the attn_combine launch. Flags zeroed
// via hipMemsetAsync between km and attn. Everything else unchanged.

typedef short bf16x8 __attribute__((ext_vector_type(8)));
typedef float f32x4 __attribute__((ext_vector_type(4)));
typedef float f32x16 __attribute__((ext_vector_type(16)));
typedef unsigned short u16x8 __attribute__((ext_vector_type(8)));
typedef unsigned int u32x4 __attribute__((ext_vector_type(4)));

typedef __attribute__((address_space(1))) const void gvoid;
typedef __attribute__((address_space(3))) void lvoid;

__device__ __forceinline__ unsigned short f2bf(float x) {
  unsigned int u = __float_as_uint(x);
  u += 0x7FFFu + ((u >> 16) & 1u);
  return (unsigned short)(u >> 16);
}
__device__ __forceinline__ float bf2f(unsigned short h) {
  return __uint_as_float(((unsigned int)h) << 16);
}
// pack two f32 -> (bf16(hi)<<16)|bf16(lo)
__device__ __forceinline__ unsigned int cvtpk(float lo, float hi) {
  unsigned int r;
  asm("v_cvt_pk_bf16_f32 %0, %1, %2" : "=v"(r) : "v"(lo), "v"(hi));
  return r;
}

__device__ __forceinline__ void gload16(const unsigned short* g, unsigned short* l) {
  __builtin_amdgcn_global_load_lds((gvoid*)g, (lvoid*)l, 16, 0, 0);
}

// Stage a [rows][64 bf16] tile (row stride 128B in LDS) from global rows of
// stride gstride. LDS dest LINEAR (global_load_lds rule); XOR swizzle
// byte^=((row&7)<<4) realized by pre-swizzling the global SOURCE address.
template <int NW>
__device__ __forceinline__ void stage_tile(const unsigned short* __restrict__ g,
                                           int gstride, unsigned short* l,
                                           int rows, int tid) {
  const int lane = tid & 63, w = tid >> 6;
  const int nch = rows << 3;  // 16B chunks
  for (int c0 = (w << 6); c0 < nch; c0 += NW * 64) {
    const int c = c0 + lane;
    const int row = c >> 3;
    const int bir = (c & 7) << 4;
    const int sb = bir ^ ((row & 7) << 4);
    gload16(g + (size_t)row * gstride + (sb >> 1), l + (size_t)c0 * 8);
  }
}

// swizzled byte offset inside a [*][64 bf16] tile
__device__ __forceinline__ int swz(int row, int byteInRow) {
  return row * 128 + (byteInRow ^ ((row & 7) << 4));
}

// ---------------------------------------------------------------------------
// prep_all: fused transpose+split of M, K, V.
// grid = (32 s-tiles, 96): y<32 -> M (t0=y*64); y<64 -> K (bh=y-32);
// y>=64 -> V (bh=y-64, hi plane only).
// ---------------------------------------------------------------------------
__global__ __launch_bounds__(256) void prep_all(
    const float* __restrict__ M, const float* __restrict__ K,
    const float* __restrict__ V, unsigned short* __restrict__ Mth,
    unsigned short* __restrict__ Mtl, unsigned short* __restrict__ Kth,
    unsigned short* __restrict__ Ktl, unsigned short* __restrict__ Vts) {
  __shared__ float Ts[64][68];
  const int s0 = blockIdx.x << 6;
  const int role = (int)blockIdx.y >> 5;   // 0=M, 1=K, 2=V
  const int yy = (int)blockIdx.y & 31;
  const int tid = threadIdx.x, r = tid >> 2, c0 = (tid & 3) << 4;

  const float* src;
  if (role == 0) {
    src = M + (size_t)(s0 + r) * 2048 + (yy << 6) + c0;
  } else {
    const int b = yy >> 3, h = yy & 7;
    const float* base = (role == 1) ? K : V;
    src = base + ((size_t)(b * 2048 + s0 + r) * 8 + h) * 64 + c0;
  }
#pragma unroll
  for (int j = 0; j < 4; ++j)
    *(float4*)&Ts[r][c0 + 4 * j] = *(const float4*)(src + 4 * j);
  __syncthreads();

  u16x8 h0, h1, l0v, l1v;
#pragma unroll
  for (int j = 0; j < 8; ++j) {
    float x = Ts[c0 + j][r];
    unsigned short hh = f2bf(x);
    h0[j] = hh; l0v[j] = f2bf(x - bf2f(hh));
  }
#pragma unroll
  for (int j = 8; j < 16; ++j) {
    float x = Ts[c0 + j][r];
    unsigned short hh = f2bf(x);
    h1[j - 8] = hh; l1v[j - 8] = f2bf(x - bf2f(hh));
  }

  if (role == 0) {
    const size_t o = (size_t)((yy << 6) + r) * 2048 + s0 + c0;
    *(u16x8*)(Mth + o) = h0; *(u16x8*)(Mth + o + 8) = h1;
    *(u16x8*)(Mtl + o) = l0v; *(u16x8*)(Mtl + o + 8) = l1v;
  } else {
    const size_t o = ((size_t)yy * 64 + r) * 2048 + s0 + c0;
    if (role == 1) {
      *(u16x8*)(Kth + o) = h0; *(u16x8*)(Kth + o + 8) = h1;
      *(u16x8*)(Ktl + o) = l0v; *(u16x8*)(Ktl + o + 8) = l1v;
    } else {
      *(u16x8*)(Vts + o) = h0; *(u16x8*)(Vts + o + 8) = h1;
    }
  }
}

// ---------------------------------------------------------------------------
// km_mfma: KM[bh][t][e] (hi/lo) = sum_s M[s][t]*K[s][e]  (proven v1)
// ---------------------------------------------------------------------------
__global__ __launch_bounds__(256) void km_mfma(
    const unsigned short* __restrict__ Mth, const unsigned short* __restrict__ Mtl,
    const unsigned short* __restrict__ Kth, const unsigned short* __restrict__ Ktl,
    unsigned short* __restrict__ KMh, unsigned short* __restrict__ KMl) {
  __shared__ __attribute__((aligned(16))) unsigned short sm[24576];  // 48 KB
  unsigned short* MtH = sm;
  unsigned short* MtL = sm + 8192;
  unsigned short* KtH = sm + 16384;
  unsigned short* KtL = sm + 20480;
  const int tid = threadIdx.x, lane = tid & 63, w = tid >> 6;
  const int g = lane >> 4, li = lane & 15;
  const int t0 = blockIdx.x << 7;
  const int bh = blockIdx.y;
  const unsigned short* KtHb = Kth + (size_t)bh * 64 * 2048;
  const unsigned short* KtLb = Ktl + (size_t)bh * 64 * 2048;

  f32x4 acc[2][4];
#pragma unroll
  for (int mi = 0; mi < 2; ++mi)
#pragma unroll
    for (int ni = 0; ni < 4; ++ni) acc[mi][ni] = (f32x4){0.f, 0.f, 0.f, 0.f};

  for (int s0 = 0; s0 < 2048; s0 += 64) {
    __syncthreads();
    stage_tile<4>(Mth + (size_t)t0 * 2048 + s0, 2048, MtH, 128, tid);
    stage_tile<4>(Mtl + (size_t)t0 * 2048 + s0, 2048, MtL, 128, tid);
    stage_tile<4>(KtHb + s0, 2048, KtH, 64, tid);
    stage_tile<4>(KtLb + s0, 2048, KtL, 64, tid);
    asm volatile("s_waitcnt vmcnt(0)" ::: "memory");
    __syncthreads();
#pragma unroll
    for (int kk = 0; kk < 2; ++kk) {
      const int kb = (kk * 32 + 8 * g) * 2;
      bf16x8 aH[2], aL[2];
#pragma unroll
      for (int mi = 0; mi < 2; ++mi) {
        const int row = (w << 5) + (mi << 4) + li;
        aH[mi] = *(const bf16x8*)((const char*)MtH + swz(row, kb));
        aL[mi] = *(const bf16x8*)((const char*)MtL + swz(row, kb));
      }
#pragma unroll
      for (int ni = 0; ni < 4; ++ni) {
        const int row = (ni << 4) + li;
        const int off = swz(row, kb);
        const bf16x8 bH = *(const bf16x8*)((const char*)KtH + off);
        const bf16x8 bL = *(const bf16x8*)((const char*)KtL + off);
#pragma unroll
        for (int mi = 0; mi < 2; ++mi) {
          acc[mi][ni] = __builtin_amdgcn_mfma_f32_16x16x32_bf16(aH[mi], bH, acc[mi][ni], 0, 0, 0);
          acc[mi][ni] = __builtin_amdgcn_mfma_f32_16x16x32_bf16(aH[mi], bL, acc[mi][ni], 0, 0, 0);
          acc[mi][ni] = __builtin_amdgcn_mfma_f32_16x16x32_bf16(aL[mi], bH, acc[mi][ni], 0, 0, 0);
        }
      }
    }
  }
  const size_t base = (size_t)bh * 2048 * 64;
#pragma unroll
  for (int mi = 0; mi < 2; ++mi)
#pragma unroll
    for (int r = 0; r < 4; ++r) {
      const int trow = t0 + (w << 5) + (mi << 4) + (g << 2) + r;
#pragma unroll
      for (int ni = 0; ni < 4; ++ni) {
        const float x = acc[mi][ni][r];
        const unsigned short hh = f2bf(x);
        const size_t idx = base + (size_t)trow * 64 + (ni << 4) + li;
        KMh[idx] = hh;
        KMl[idx] = f2bf(x - bf2f(hh));
      }
    }
}

// ---------------------------------------------------------------------------
// attn32: 768 blocks. bid -> x=bid&7 (XCD), n=bid>>3, slot=n>>5, j=n&31,
// bh=(x<<2)|(j&3), k=j>>2.  slot 2: full q-tile lt=k (2k+2 tiles).
// slot 0/1: q-tile lt=15-k, kv half `slot` (16-k tiles each) -> partials;
// SECOND finisher of each (bh,k) pair merges in-kernel (replaces combine).
// ---------------------------------------------------------------------------
__global__ __launch_bounds__(256, 3) void attn32(
    const float* __restrict__ Q, const unsigned short* __restrict__ KMh,
    const unsigned short* __restrict__ KMl, const unsigned short* __restrict__ Vt,
    float* __restrict__ Out, float* __restrict__ Opart, float* __restrict__ Ml,
    int* __restrict__ flags) {
  // LDS: 2 staging buffers x {KH 8KB, KL 8KB, VT 8KB} = 48KB
  __shared__ __attribute__((aligned(16))) unsigned short sm[24576];
  __shared__ int who;
  const int tid = threadIdx.x, lane = tid & 63, w = tid >> 6;
  const int g2 = lane >> 5, li5 = lane & 31;

  const int bid = (int)blockIdx.x;
  const int x = bid & 7, n = bid >> 3;
  const int slot = n >> 5, j = n & 31;
  const int bh = (x << 2) | (j & 3);
  const int kk = j >> 2;
  int lt, jt0, jtEnd;
  bool partial;
  if (slot == 2) {
    lt = kk; jt0 = 0; jtEnd = 2 * kk + 1; partial = false;
  } else {
    lt = 15 - kk;
    const int half = 16 - kk;
    jt0 = slot * half; jtEnd = jt0 + half - 1; partial = true;
  }
  const int b = bh >> 3, h = bh & 7;
  const int l0 = lt << 7;
  const int qg = l0 + (w << 5) + li5;
  const int rloc = (w << 5) + li5;

  // Q fragments (hi/lo) in registers, pre-scaled by 0.125*log2(e).
  const float SC2 = 0.18033688011112042f;
  bf16x8 qh[4], ql[4];
  {
    const float* qsrc = Q + (((size_t)(b * 2048 + qg) * 8 + h) << 6) + (g2 << 3);
#pragma unroll
    for (int kki = 0; kki < 4; ++kki) {
      const float4 v0 = *(const float4*)(qsrc + 16 * kki);
      const float4 v1 = *(const float4*)(qsrc + 16 * kki + 4);
      const float xs[8] = {v0.x, v0.y, v0.z, v0.w, v1.x, v1.y, v1.z, v1.w};
#pragma unroll
      for (int jj = 0; jj < 8; ++jj) {
        const float xv = xs[jj] * SC2;
        const unsigned short hh = f2bf(xv);
        qh[kki][jj] = (short)hh;
        ql[kki][jj] = (short)f2bf(xv - bf2f(hh));
      }
    }
  }

  f32x16 o0 = {0,0,0,0,0,0,0,0,0,0,0,0,0,0,0,0};
  f32x16 o1 = {0,0,0,0,0,0,0,0,0,0,0,0,0,0,0,0};
  f32x16 lsacc = {0,0,0,0,0,0,0,0,0,0,0,0,0,0,0,0};
  float m2 = -1e30f;
  bf16x8 ones;
#pragma unroll
  for (int jj = 0; jj < 8; ++jj) ones[jj] = (short)0x3F80;  // bf16 1.0

  const unsigned short* KHb = KMh + (size_t)bh * 2048 * 64;
  const unsigned short* KLb = KMl + (size_t)bh * 2048 * 64;
  const unsigned short* VTb = Vt + (size_t)bh * 64 * 2048;

  const int jtmax_w = 2 * lt + (w >> 1);

  // prologue: stage tile jt0
  {
    unsigned short* s0b = sm + (jt0 & 1) * 12288;
    stage_tile<4>(KHb + (size_t)jt0 * 4096, 64, s0b, 64, tid);
    stage_tile<4>(KLb + (size_t)jt0 * 4096, 64, s0b + 4096, 64, tid);
    stage_tile<4>(VTb + jt0 * 64, 2048, s0b + 8192, 64, tid);
  }
  asm volatile("s_waitcnt vmcnt(0)" ::: "memory");
  __builtin_amdgcn_s_barrier();
  __builtin_amdgcn_sched_barrier(0);

  for (int jt = jt0; jt <= jtEnd; ++jt) {
    const int cur = jt & 1;
    // prefetch next tile into the other buffer (overlaps this tile's compute)
    if (jt < jtEnd) {
      unsigned short* nb = sm + (cur ^ 1) * 12288;
      stage_tile<4>(KHb + (size_t)(jt + 1) * 4096, 64, nb, 64, tid);
      stage_tile<4>(KLb + (size_t)(jt + 1) * 4096, 64, nb + 4096, 64, tid);
      stage_tile<4>(VTb + (jt + 1) * 64, 2048, nb + 8192, 64, tid);
    }

    if (jt <= jtmax_w) {
      const unsigned short* KH = sm + cur * 12288;
      const unsigned short* KL = KH + 4096;
      const unsigned short* VT = KH + 8192;

      // z = KM * Q : A = KM[t][e] rows (2 t-frags), B = Q regs (pre-scaled)
      f32x16 z0 = {0,0,0,0,0,0,0,0,0,0,0,0,0,0,0,0};
      f32x16 z1 = {0,0,0,0,0,0,0,0,0,0,0,0,0,0,0,0};
      __builtin_amdgcn_s_setprio(1);
#pragma unroll
      for (int kki = 0; kki < 4; ++kki) {
        const int cb = 32 * kki + 16 * g2;
        const bf16x8 a0h = *(const bf16x8*)((const char*)KH + swz(li5, cb));
        const bf16x8 a0l = *(const bf16x8*)((const char*)KL + swz(li5, cb));
        const bf16x8 a1h = *(const bf16x8*)((const char*)KH + swz(32 + li5, cb));
        const bf16x8 a1l = *(const bf16x8*)((const char*)KL + swz(32 + li5, cb));
        z0 = __builtin_amdgcn_mfma_f32_32x32x16_bf16(a0h, qh[kki], z0, 0, 0, 0);
        z0 = __builtin_amdgcn_mfma_f32_32x32x16_bf16(a0h, ql[kki], z0, 0, 0, 0);
        z0 = __builtin_amdgcn_mfma_f32_32x32x16_bf16(a0l, qh[kki], z0, 0, 0, 0);
        z1 = __builtin_amdgcn_mfma_f32_32x32x16_bf16(a1h, qh[kki], z1, 0, 0, 0);
        z1 = __builtin_amdgcn_mfma_f32_32x32x16_bf16(a1h, ql[kki], z1, 0, 0, 0);
        z1 = __builtin_amdgcn_mfma_f32_32x32x16_bf16(a1l, qh[kki], z1, 0, 0, 0);
      }
      __builtin_amdgcn_s_setprio(0);

      // causal mask (z pre-scaled; select only)
      const bool needmask = (jt * 64 + 63 > l0 + (w << 5));
      if (needmask) {
        const int thr = qg - jt * 64;  // mask if t_loc > thr
#pragma unroll
        for (int rr = 0; rr < 16; ++rr) {
          const int tl = (g2 << 2) + ((rr >> 2) << 3) + (rr & 3);
          if (tl > thr) z0[rr] = -1e30f;
          if (tl + 32 > thr) z1[rr] = -1e30f;
        }
      }

      // running max with deferred rescale (THR=11 in log2 domain)
      float t16[16];
#pragma unroll
      for (int rr = 0; rr < 16; ++rr) t16[rr] = fmaxf(z0[rr], z1[rr]);
#pragma unroll
      for (int s = 8; s; s >>= 1)
#pragma unroll
        for (int rr = 0; rr < 8; ++rr)
          if (rr < s) t16[rr] = fmaxf(t16[rr], t16[rr + s]);
      const float mx = fmaxf(t16[0], __shfl_xor(t16[0], 32));
      if (__any(mx > m2 + 11.0f)) {
        const float m2n = fmaxf(m2, mx);
        const float fs = exp2f(m2 - m2n);
        m2 = m2n;
#pragma unroll
        for (int rr = 0; rr < 16; ++rr) { o0[rr] *= fs; o1[rr] *= fs; }
        lsacc[0] *= fs;
      }

      // P = exp2(z - m2), packed to bf16 pairs in-register
      float pv0[16], pv1[16];
#pragma unroll
      for (int rr = 0; rr < 16; ++rr) {
        pv0[rr] = exp2f(z0[rr] - m2);
        pv1[rr] = exp2f(z1[rr] - m2);
      }
      unsigned int W0[8], W1[8];
#pragma unroll
      for (int i = 0; i < 8; ++i) {
        W0[i] = cvtpk(pv0[2 * i], pv0[2 * i + 1]);
        W1[i] = cvtpk(pv1[2 * i], pv1[2 * i + 1]);
      }
      // cross-half exchange: words [0..3] -> frag kk, [4..7] -> frag kk+1
      asm volatile("v_permlane32_swap_b32 %0, %1" : "+v"(W0[0]), "+v"(W0[2]));
      asm volatile("v_permlane32_swap_b32 %0, %1" : "+v"(W0[1]), "+v"(W0[3]));
      asm volatile("v_permlane32_swap_b32 %0, %1" : "+v"(W0[4]), "+v"(W0[6]));
      asm volatile("v_permlane32_swap_b32 %0, %1" : "+v"(W0[5]), "+v"(W0[7]));
      asm volatile("v_permlane32_swap_b32 %0, %1" : "+v"(W1[0]), "+v"(W1[2]));
      asm volatile("v_permlane32_swap_b32 %0, %1" : "+v"(W1[1]), "+v"(W1[3]));
      asm volatile("v_permlane32_swap_b32 %0, %1" : "+v"(W1[4]), "+v"(W1[6]));
      asm volatile("v_permlane32_swap_b32 %0, %1" : "+v"(W1[5]), "+v"(W1[7]));
      bf16x8 pf[4];
      {
        u32x4 f0 = {W0[0], W0[1], W0[2], W0[3]};
        u32x4 f1 = {W0[4], W0[5], W0[6], W0[7]};
        u32x4 f2 = {W1[0], W1[1], W1[2], W1[3]};
        u32x4 f3 = {W1[4], W1[5], W1[6], W1[7]};
        pf[0] = __builtin_bit_cast(bf16x8, f0);
        pf[1] = __builtin_bit_cast(bf16x8, f1);
        pf[2] = __builtin_bit_cast(bf16x8, f2);
        pf[3] = __builtin_bit_cast(bf16x8, f3);
      }

      // O += V^T * P ; lsum += ones * P   (P from registers)
      __builtin_amdgcn_s_setprio(1);
#pragma unroll
      for (int kki = 0; kki < 4; ++kki) {
        const int cb = 32 * kki + 16 * g2;
        const bf16x8 v0f = *(const bf16x8*)((const char*)VT + swz(li5, cb));
        const bf16x8 v1f = *(const bf16x8*)((const char*)VT + swz(32 + li5, cb));
        o0 = __builtin_amdgcn_mfma_f32_32x32x16_bf16(v0f, pf[kki], o0, 0, 0, 0);
        o1 = __builtin_amdgcn_mfma_f32_32x32x16_bf16(v1f, pf[kki], o1, 0, 0, 0);
        lsacc = __builtin_amdgcn_mfma_f32_32x32x16_bf16(ones, pf[kki], lsacc, 0, 0, 0);
      }
      __builtin_amdgcn_s_setprio(0);
    }

    // end-of-tile: drain this tile's prefetch, then block-wide barrier.
    asm volatile("s_waitcnt vmcnt(0)" ::: "memory");
    __builtin_amdgcn_s_barrier();
    __builtin_amdgcn_sched_barrier(0);
  }

  if (!partial) {
    // normalize + store. d = df*32 + 4*g2 + 8*r2 + rr
    const float inv = 1.f / lsacc[0];
    float* ob = Out + (((size_t)(b * 2048 + qg) * 8 + h) << 6);
#pragma unroll
    for (int r2 = 0; r2 < 4; ++r2) {
      const int doff = (g2 << 2) + (r2 << 3);
      float4 s0 = make_float4(o0[4 * r2] * inv, o0[4 * r2 + 1] * inv,
                              o0[4 * r2 + 2] * inv, o0[4 * r2 + 3] * inv);
      *(float4*)(ob + doff) = s0;
      float4 s1 = make_float4(o1[4 * r2] * inv, o1[4 * r2 + 1] * inv,
                              o1[4 * r2 + 2] * inv, o1[4 * r2 + 3] * inv);
      *(float4*)(ob + 32 + doff) = s1;
    }
  } else {
    // raw partial: O (unnormalized), m2, lsum
    const size_t pidx = (((size_t)slot * 32 + bh) * 8 + kk) * 128 + rloc;
    float* op = Opart + pidx * 64;
#pragma unroll
    for (int r2 = 0; r2 < 4; ++r2) {
      const int doff = (g2 << 2) + (r2 << 3);
      *(float4*)(op + doff) =
          make_float4(o0[4 * r2], o0[4 * r2 + 1], o0[4 * r2 + 2], o0[4 * r2 + 3]);
      *(float4*)(op + 32 + doff) =
          make_float4(o1[4 * r2], o1[4 * r2 + 1], o1[4 * r2 + 2], o1[4 * r2 + 3]);
    }
    Ml[pidx * 2] = m2;
    Ml[pidx * 2 + 1] = lsacc[0];

    // last-finisher merge (replaces the attn_combine kernel)
    __syncthreads();  // all of this block's partial stores drained (vmcnt 0)
    if (tid == 0) {
      __threadfence();  // release partials device-wide (wb L2)
      who = atomicAdd(&flags[(bh << 3) + kk], 1);
      __threadfence();  // acquire the other block's partials (inv caches)
    }
    __syncthreads();
    if (who == 1) {
      const size_t PSLOT = (size_t)32 * 8 * 128 * 64;
      const size_t MSLOT = (size_t)32 * 8 * 128 * 2;
#pragma unroll
      for (int p = 0; p < 4; ++p) {
        const int r = (p << 5) + (tid >> 3);
        const int d0 = (tid & 7) << 3;
        const size_t pix = (((size_t)bh * 8 + kk) * 128 + r);
        const float m0 = Ml[pix * 2], ls0 = Ml[pix * 2 + 1];
        const float m1 = Ml[MSLOT + pix * 2], ls1 = Ml[MSLOT + pix * 2 + 1];
        const float mm = fmaxf(m0, m1);
        const float w0 = exp2f(m0 - mm), w1 = exp2f(m1 - mm);
        const float inv = 1.f / (ls0 * w0 + ls1 * w1);
        const float* p0 = Opart + pix * 64 + d0;
        const float* p1 = Opart + PSLOT + pix * 64 + d0;
        const float4 a0 = *(const float4*)(p0);
        const float4 a1 = *(const float4*)(p0 + 4);
        const float4 b0 = *(const float4*)(p1);
        const float4 b1 = *(const float4*)(p1 + 4);
        const int qgm = l0 + r;  // lt == 15-kk for partial blocks
        float* o = Out + (((size_t)(b * 2048 + qgm) * 8 + h) << 6) + d0;
        *(float4*)o = make_float4((a0.x * w0 + b0.x * w1) * inv,
                                  (a0.y * w0 + b0.y * w1) * inv,
                                  (a0.z * w0 + b0.z * w1) * inv,
                                  (a0.w * w0 + b0.w * w1) * inv);
        *(float4*)(o + 4) = make_float4((a1.x * w0 + b1.x * w1) * inv,
                                        (a1.y * w0 + b1.y * w1) * inv,
                                        (a1.z * w0 + b1.z * w1) * inv,
                                        (a1.w * w0 + b1.w * w1) * inv);
      }
    }
  }
}

extern "C" void kernel_launch(void* const* d_in, const int* in_sizes, int n_in,
                              void* d_out, int out_size, void* d_ws, size_t ws_size,
                              hipStream_t stream) {
  const float* Q = (const float*)d_in[0];
  const float* K = (const float*)d_in[1];
  const float* V = (const float*)d_in[2];
  const float* M = (const float*)d_in[3];
  float* Out = (float*)d_out;
  char* ws = (char*)d_ws;
  const size_t MB = 1u << 20;
  unsigned short* Mth = (unsigned short*)(ws);            // [2048 t][2048 s]
  unsigned short* Mtl = (unsigned short*)(ws + 8 * MB);
  unsigned short* Kth = (unsigned short*)(ws + 16 * MB);  // [32 bh][64 e][2048 s]
  unsigned short* Ktl = (unsigned short*)(ws + 24 * MB);
  unsigned short* Vts = (unsigned short*)(ws + 32 * MB);  // [32 bh][64 d][2048 s]
  unsigned short* KMh = (unsigned short*)(ws + 40 * MB);  // [32 bh][2048 t][64 e]
  unsigned short* KMl = (unsigned short*)(ws + 48 * MB);
  // attn partials overlay the (dead after km) M/K staging regions:
  float* Opart = (float*)(ws);                            // 2 x 8MB
  float* Mlp = (float*)(ws + 16 * MB);                    // 512 KB
  int* flags = (int*)(ws + 16 * MB + 512 * 1024);         // 256 ints (dead Kth)

  prep_all<<<dim3(32, 96), 256, 0, stream>>>(M, K, V, Mth, Mtl, Kth, Ktl, Vts);
  km_mfma<<<dim3(16, 32), 256, 0, stream>>>(Mth, Mtl, Kth, Ktl, KMh, KMl);
  hipMemsetAsync(flags, 0, 256 * sizeof(int), stream);
  attn32<<<dim3(768), 256, 0, stream>>>(Q, KMh, KMl, Vts, Out, Opart, Mlp, flags);
}

// Round 12
// 139.051 us; speedup vs baseline: 1.1748x; 1.1748x over previous
//
#include <hip/hip_runtime.h>

// B=4, L=S=2048, H=8, E=D=64.  KM[bh][t][e] = sum_s K[b,s,h,e]*M[s,t] (split
// bf16 hi/lo), then flash attention z = Q*KM/8, causal, online softmax.
// Round 12: revert round-11's fence-based merge (L2-equilibrium destruction,
// +24us). Round-10 pipeline (proven 139.7us) + bf16 partials (verified
// numerics in rounds 8/9): halves Opart traffic in attn epilogue + combine.

typedef short bf16x8 __attribute__((ext_vector_type(8)));
typedef float f32x4 __attribute__((ext_vector_type(4)));
typedef float f32x16 __attribute__((ext_vector_type(16)));
typedef unsigned short u16x8 __attribute__((ext_vector_type(8)));
typedef unsigned int u32x4 __attribute__((ext_vector_type(4)));

typedef __attribute__((address_space(1))) const void gvoid;
typedef __attribute__((address_space(3))) void lvoid;

__device__ __forceinline__ unsigned short f2bf(float x) {
  unsigned int u = __float_as_uint(x);
  u += 0x7FFFu + ((u >> 16) & 1u);
  return (unsigned short)(u >> 16);
}
__device__ __forceinline__ float bf2f(unsigned short h) {
  return __uint_as_float(((unsigned int)h) << 16);
}
// pack two f32 -> (bf16(hi)<<16)|bf16(lo)
__device__ __forceinline__ unsigned int cvtpk(float lo, float hi) {
  unsigned int r;
  asm("v_cvt_pk_bf16_f32 %0, %1, %2" : "=v"(r) : "v"(lo), "v"(hi));
  return r;
}

__device__ __forceinline__ void gload16(const unsigned short* g, unsigned short* l) {
  __builtin_amdgcn_global_load_lds((gvoid*)g, (lvoid*)l, 16, 0, 0);
}

// Stage a [rows][64 bf16] tile (row stride 128B in LDS) from global rows of
// stride gstride. LDS dest LINEAR (global_load_lds rule); XOR swizzle
// byte^=((row&7)<<4) realized by pre-swizzling the global SOURCE address.
template <int NW>
__device__ __forceinline__ void stage_tile(const unsigned short* __restrict__ g,
                                           int gstride, unsigned short* l,
                                           int rows, int tid) {
  const int lane = tid & 63, w = tid >> 6;
  const int nch = rows << 3;  // 16B chunks
  for (int c0 = (w << 6); c0 < nch; c0 += NW * 64) {
    const int c = c0 + lane;
    const int row = c >> 3;
    const int bir = (c & 7) << 4;
    const int sb = bir ^ ((row & 7) << 4);
    gload16(g + (size_t)row * gstride + (sb >> 1), l + (size_t)c0 * 8);
  }
}

// swizzled byte offset inside a [*][64 bf16] tile
__device__ __forceinline__ int swz(int row, int byteInRow) {
  return row * 128 + (byteInRow ^ ((row & 7) << 4));
}

// ---------------------------------------------------------------------------
// prep_all: fused transpose+split of M, K, V.
// grid = (32 s-tiles, 96): y<32 -> M (t0=y*64); y<64 -> K (bh=y-32);
// y>=64 -> V (bh=y-64, hi plane only).
// ---------------------------------------------------------------------------
__global__ __launch_bounds__(256) void prep_all(
    const float* __restrict__ M, const float* __restrict__ K,
    const float* __restrict__ V, unsigned short* __restrict__ Mth,
    unsigned short* __restrict__ Mtl, unsigned short* __restrict__ Kth,
    unsigned short* __restrict__ Ktl, unsigned short* __restrict__ Vts) {
  __shared__ float Ts[64][68];
  const int s0 = blockIdx.x << 6;
  const int role = (int)blockIdx.y >> 5;   // 0=M, 1=K, 2=V
  const int yy = (int)blockIdx.y & 31;
  const int tid = threadIdx.x, r = tid >> 2, c0 = (tid & 3) << 4;

  const float* src;
  if (role == 0) {
    src = M + (size_t)(s0 + r) * 2048 + (yy << 6) + c0;
  } else {
    const int b = yy >> 3, h = yy & 7;
    const float* base = (role == 1) ? K : V;
    src = base + ((size_t)(b * 2048 + s0 + r) * 8 + h) * 64 + c0;
  }
#pragma unroll
  for (int j = 0; j < 4; ++j)
    *(float4*)&Ts[r][c0 + 4 * j] = *(const float4*)(src + 4 * j);
  __syncthreads();

  u16x8 h0, h1, l0v, l1v;
#pragma unroll
  for (int j = 0; j < 8; ++j) {
    float x = Ts[c0 + j][r];
    unsigned short hh = f2bf(x);
    h0[j] = hh; l0v[j] = f2bf(x - bf2f(hh));
  }
#pragma unroll
  for (int j = 8; j < 16; ++j) {
    float x = Ts[c0 + j][r];
    unsigned short hh = f2bf(x);
    h1[j - 8] = hh; l1v[j - 8] = f2bf(x - bf2f(hh));
  }

  if (role == 0) {
    const size_t o = (size_t)((yy << 6) + r) * 2048 + s0 + c0;
    *(u16x8*)(Mth + o) = h0; *(u16x8*)(Mth + o + 8) = h1;
    *(u16x8*)(Mtl + o) = l0v; *(u16x8*)(Mtl + o + 8) = l1v;
  } else {
    const size_t o = ((size_t)yy * 64 + r) * 2048 + s0 + c0;
    if (role == 1) {
      *(u16x8*)(Kth + o) = h0; *(u16x8*)(Kth + o + 8) = h1;
      *(u16x8*)(Ktl + o) = l0v; *(u16x8*)(Ktl + o + 8) = l1v;
    } else {
      *(u16x8*)(Vts + o) = h0; *(u16x8*)(Vts + o + 8) = h1;
    }
  }
}

// ---------------------------------------------------------------------------
// km_mfma: KM[bh][t][e] (hi/lo) = sum_s M[s][t]*K[s][e]  (proven v1)
// ---------------------------------------------------------------------------
__global__ __launch_bounds__(256) void km_mfma(
    const unsigned short* __restrict__ Mth, const unsigned short* __restrict__ Mtl,
    const unsigned short* __restrict__ Kth, const unsigned short* __restrict__ Ktl,
    unsigned short* __restrict__ KMh, unsigned short* __restrict__ KMl) {
  __shared__ __attribute__((aligned(16))) unsigned short sm[24576];  // 48 KB
  unsigned short* MtH = sm;
  unsigned short* MtL = sm + 8192;
  unsigned short* KtH = sm + 16384;
  unsigned short* KtL = sm + 20480;
  const int tid = threadIdx.x, lane = tid & 63, w = tid >> 6;
  const int g = lane >> 4, li = lane & 15;
  const int t0 = blockIdx.x << 7;
  const int bh = blockIdx.y;
  const unsigned short* KtHb = Kth + (size_t)bh * 64 * 2048;
  const unsigned short* KtLb = Ktl + (size_t)bh * 64 * 2048;

  f32x4 acc[2][4];
#pragma unroll
  for (int mi = 0; mi < 2; ++mi)
#pragma unroll
    for (int ni = 0; ni < 4; ++ni) acc[mi][ni] = (f32x4){0.f, 0.f, 0.f, 0.f};

  for (int s0 = 0; s0 < 2048; s0 += 64) {
    __syncthreads();
    stage_tile<4>(Mth + (size_t)t0 * 2048 + s0, 2048, MtH, 128, tid);
    stage_tile<4>(Mtl + (size_t)t0 * 2048 + s0, 2048, MtL, 128, tid);
    stage_tile<4>(KtHb + s0, 2048, KtH, 64, tid);
    stage_tile<4>(KtLb + s0, 2048, KtL, 64, tid);
    asm volatile("s_waitcnt vmcnt(0)" ::: "memory");
    __syncthreads();
#pragma unroll
    for (int kk = 0; kk < 2; ++kk) {
      const int kb = (kk * 32 + 8 * g) * 2;
      bf16x8 aH[2], aL[2];
#pragma unroll
      for (int mi = 0; mi < 2; ++mi) {
        const int row = (w << 5) + (mi << 4) + li;
        aH[mi] = *(const bf16x8*)((const char*)MtH + swz(row, kb));
        aL[mi] = *(const bf16x8*)((const char*)MtL + swz(row, kb));
      }
#pragma unroll
      for (int ni = 0; ni < 4; ++ni) {
        const int row = (ni << 4) + li;
        const int off = swz(row, kb);
        const bf16x8 bH = *(const bf16x8*)((const char*)KtH + off);
        const bf16x8 bL = *(const bf16x8*)((const char*)KtL + off);
#pragma unroll
        for (int mi = 0; mi < 2; ++mi) {
          acc[mi][ni] = __builtin_amdgcn_mfma_f32_16x16x32_bf16(aH[mi], bH, acc[mi][ni], 0, 0, 0);
          acc[mi][ni] = __builtin_amdgcn_mfma_f32_16x16x32_bf16(aH[mi], bL, acc[mi][ni], 0, 0, 0);
          acc[mi][ni] = __builtin_amdgcn_mfma_f32_16x16x32_bf16(aL[mi], bH, acc[mi][ni], 0, 0, 0);
        }
      }
    }
  }
  const size_t base = (size_t)bh * 2048 * 64;
#pragma unroll
  for (int mi = 0; mi < 2; ++mi)
#pragma unroll
    for (int r = 0; r < 4; ++r) {
      const int trow = t0 + (w << 5) + (mi << 4) + (g << 2) + r;
#pragma unroll
      for (int ni = 0; ni < 4; ++ni) {
        const float x = acc[mi][ni][r];
        const unsigned short hh = f2bf(x);
        const size_t idx = base + (size_t)trow * 64 + (ni << 4) + li;
        KMh[idx] = hh;
        KMl[idx] = f2bf(x - bf2f(hh));
      }
    }
}

// ---------------------------------------------------------------------------
// attn32: 768 blocks. bid -> x=bid&7 (XCD), n=bid>>3, slot=n>>5, j=n&31,
// bh=(x<<2)|(j&3), k=j>>2.  slot 2: full q-tile lt=k (2k+2 tiles).
// slot 0/1: q-tile lt=15-k, kv half `slot` (16-k tiles each), partial output
// (bf16 O + fp32 m/lsum). Each CU's 3 slots: (16-k)+(16-k)+(2k+2) = 34 tiles.
// ---------------------------------------------------------------------------
__global__ __launch_bounds__(256, 3) void attn32(
    const float* __restrict__ Q, const unsigned short* __restrict__ KMh,
    const unsigned short* __restrict__ KMl, const unsigned short* __restrict__ Vt,
    float* __restrict__ Out, unsigned short* __restrict__ Opart,
    float* __restrict__ Ml) {
  // LDS: 2 staging buffers x {KH 8KB, KL 8KB, VT 8KB} = 48KB
  __shared__ __attribute__((aligned(16))) unsigned short sm[24576];
  const int tid = threadIdx.x, lane = tid & 63, w = tid >> 6;
  const int g2 = lane >> 5, li5 = lane & 31;

  const int bid = (int)blockIdx.x;
  const int x = bid & 7, n = bid >> 3;
  const int slot = n >> 5, j = n & 31;
  const int bh = (x << 2) | (j & 3);
  const int kk = j >> 2;
  int lt, jt0, jtEnd;
  bool partial;
  if (slot == 2) {
    lt = kk; jt0 = 0; jtEnd = 2 * kk + 1; partial = false;
  } else {
    lt = 15 - kk;
    const int half = 16 - kk;
    jt0 = slot * half; jtEnd = jt0 + half - 1; partial = true;
  }
  const int b = bh >> 3, h = bh & 7;
  const int l0 = lt << 7;
  const int qg = l0 + (w << 5) + li5;
  const int rloc = (w << 5) + li5;

  // Q fragments (hi/lo) in registers, pre-scaled by 0.125*log2(e).
  const float SC2 = 0.18033688011112042f;
  bf16x8 qh[4], ql[4];
  {
    const float* qsrc = Q + (((size_t)(b * 2048 + qg) * 8 + h) << 6) + (g2 << 3);
#pragma unroll
    for (int kki = 0; kki < 4; ++kki) {
      const float4 v0 = *(const float4*)(qsrc + 16 * kki);
      const float4 v1 = *(const float4*)(qsrc + 16 * kki + 4);
      const float xs[8] = {v0.x, v0.y, v0.z, v0.w, v1.x, v1.y, v1.z, v1.w};
#pragma unroll
      for (int jj = 0; jj < 8; ++jj) {
        const float xv = xs[jj] * SC2;
        const unsigned short hh = f2bf(xv);
        qh[kki][jj] = (short)hh;
        ql[kki][jj] = (short)f2bf(xv - bf2f(hh));
      }
    }
  }

  f32x16 o0 = {0,0,0,0,0,0,0,0,0,0,0,0,0,0,0,0};
  f32x16 o1 = {0,0,0,0,0,0,0,0,0,0,0,0,0,0,0,0};
  f32x16 lsacc = {0,0,0,0,0,0,0,0,0,0,0,0,0,0,0,0};
  float m2 = -1e30f;
  bf16x8 ones;
#pragma unroll
  for (int jj = 0; jj < 8; ++jj) ones[jj] = (short)0x3F80;  // bf16 1.0

  const unsigned short* KHb = KMh + (size_t)bh * 2048 * 64;
  const unsigned short* KLb = KMl + (size_t)bh * 2048 * 64;
  const unsigned short* VTb = Vt + (size_t)bh * 64 * 2048;

  const int jtmax_w = 2 * lt + (w >> 1);

  // prologue: stage tile jt0
  {
    unsigned short* s0b = sm + (jt0 & 1) * 12288;
    stage_tile<4>(KHb + (size_t)jt0 * 4096, 64, s0b, 64, tid);
    stage_tile<4>(KLb + (size_t)jt0 * 4096, 64, s0b + 4096, 64, tid);
    stage_tile<4>(VTb + jt0 * 64, 2048, s0b + 8192, 64, tid);
  }
  asm volatile("s_waitcnt vmcnt(0)" ::: "memory");
  __builtin_amdgcn_s_barrier();
  __builtin_amdgcn_sched_barrier(0);

  for (int jt = jt0; jt <= jtEnd; ++jt) {
    const int cur = jt & 1;
    // prefetch next tile into the other buffer (overlaps this tile's compute)
    if (jt < jtEnd) {
      unsigned short* nb = sm + (cur ^ 1) * 12288;
      stage_tile<4>(KHb + (size_t)(jt + 1) * 4096, 64, nb, 64, tid);
      stage_tile<4>(KLb + (size_t)(jt + 1) * 4096, 64, nb + 4096, 64, tid);
      stage_tile<4>(VTb + (jt + 1) * 64, 2048, nb + 8192, 64, tid);
    }

    if (jt <= jtmax_w) {
      const unsigned short* KH = sm + cur * 12288;
      const unsigned short* KL = KH + 4096;
      const unsigned short* VT = KH + 8192;

      // z = KM * Q : A = KM[t][e] rows (2 t-frags), B = Q regs (pre-scaled)
      f32x16 z0 = {0,0,0,0,0,0,0,0,0,0,0,0,0,0,0,0};
      f32x16 z1 = {0,0,0,0,0,0,0,0,0,0,0,0,0,0,0,0};
      __builtin_amdgcn_s_setprio(1);
#pragma unroll
      for (int kki = 0; kki < 4; ++kki) {
        const int cb = 32 * kki + 16 * g2;
        const bf16x8 a0h = *(const bf16x8*)((const char*)KH + swz(li5, cb));
        const bf16x8 a0l = *(const bf16x8*)((const char*)KL + swz(li5, cb));
        const bf16x8 a1h = *(const bf16x8*)((const char*)KH + swz(32 + li5, cb));
        const bf16x8 a1l = *(const bf16x8*)((const char*)KL + swz(32 + li5, cb));
        z0 = __builtin_amdgcn_mfma_f32_32x32x16_bf16(a0h, qh[kki], z0, 0, 0, 0);
        z0 = __builtin_amdgcn_mfma_f32_32x32x16_bf16(a0h, ql[kki], z0, 0, 0, 0);
        z0 = __builtin_amdgcn_mfma_f32_32x32x16_bf16(a0l, qh[kki], z0, 0, 0, 0);
        z1 = __builtin_amdgcn_mfma_f32_32x32x16_bf16(a1h, qh[kki], z1, 0, 0, 0);
        z1 = __builtin_amdgcn_mfma_f32_32x32x16_bf16(a1h, ql[kki], z1, 0, 0, 0);
        z1 = __builtin_amdgcn_mfma_f32_32x32x16_bf16(a1l, qh[kki], z1, 0, 0, 0);
      }
      __builtin_amdgcn_s_setprio(0);

      // causal mask (z pre-scaled; select only)
      const bool needmask = (jt * 64 + 63 > l0 + (w << 5));
      if (needmask) {
        const int thr = qg - jt * 64;  // mask if t_loc > thr
#pragma unroll
        for (int rr = 0; rr < 16; ++rr) {
          const int tl = (g2 << 2) + ((rr >> 2) << 3) + (rr & 3);
          if (tl > thr) z0[rr] = -1e30f;
          if (tl + 32 > thr) z1[rr] = -1e30f;
        }
      }

      // running max with deferred rescale (THR=11 in log2 domain)
      float t16[16];
#pragma unroll
      for (int rr = 0; rr < 16; ++rr) t16[rr] = fmaxf(z0[rr], z1[rr]);
#pragma unroll
      for (int s = 8; s; s >>= 1)
#pragma unroll
        for (int rr = 0; rr < 8; ++rr)
          if (rr < s) t16[rr] = fmaxf(t16[rr], t16[rr + s]);
      const float mx = fmaxf(t16[0], __shfl_xor(t16[0], 32));
      if (__any(mx > m2 + 11.0f)) {
        const float m2n = fmaxf(m2, mx);
        const float fs = exp2f(m2 - m2n);
        m2 = m2n;
#pragma unroll
        for (int rr = 0; rr < 16; ++rr) { o0[rr] *= fs; o1[rr] *= fs; }
        lsacc[0] *= fs;
      }

      // P = exp2(z - m2), packed to bf16 pairs in-register
      float pv0[16], pv1[16];
#pragma unroll
      for (int rr = 0; rr < 16; ++rr) {
        pv0[rr] = exp2f(z0[rr] - m2);
        pv1[rr] = exp2f(z1[rr] - m2);
      }
      unsigned int W0[8], W1[8];
#pragma unroll
      for (int i = 0; i < 8; ++i) {
        W0[i] = cvtpk(pv0[2 * i], pv0[2 * i + 1]);
        W1[i] = cvtpk(pv1[2 * i], pv1[2 * i + 1]);
      }
      // cross-half exchange: words [0..3] -> frag kk, [4..7] -> frag kk+1
      asm volatile("v_permlane32_swap_b32 %0, %1" : "+v"(W0[0]), "+v"(W0[2]));
      asm volatile("v_permlane32_swap_b32 %0, %1" : "+v"(W0[1]), "+v"(W0[3]));
      asm volatile("v_permlane32_swap_b32 %0, %1" : "+v"(W0[4]), "+v"(W0[6]));
      asm volatile("v_permlane32_swap_b32 %0, %1" : "+v"(W0[5]), "+v"(W0[7]));
      asm volatile("v_permlane32_swap_b32 %0, %1" : "+v"(W1[0]), "+v"(W1[2]));
      asm volatile("v_permlane32_swap_b32 %0, %1" : "+v"(W1[1]), "+v"(W1[3]));
      asm volatile("v_permlane32_swap_b32 %0, %1" : "+v"(W1[4]), "+v"(W1[6]));
      asm volatile("v_permlane32_swap_b32 %0, %1" : "+v"(W1[5]), "+v"(W1[7]));
      bf16x8 pf[4];
      {
        u32x4 f0 = {W0[0], W0[1], W0[2], W0[3]};
        u32x4 f1 = {W0[4], W0[5], W0[6], W0[7]};
        u32x4 f2 = {W1[0], W1[1], W1[2], W1[3]};
        u32x4 f3 = {W1[4], W1[5], W1[6], W1[7]};
        pf[0] = __builtin_bit_cast(bf16x8, f0);
        pf[1] = __builtin_bit_cast(bf16x8, f1);
        pf[2] = __builtin_bit_cast(bf16x8, f2);
        pf[3] = __builtin_bit_cast(bf16x8, f3);
      }

      // O += V^T * P ; lsum += ones * P   (P from registers)
      __builtin_amdgcn_s_setprio(1);
#pragma unroll
      for (int kki = 0; kki < 4; ++kki) {
        const int cb = 32 * kki + 16 * g2;
        const bf16x8 v0f = *(const bf16x8*)((const char*)VT + swz(li5, cb));
        const bf16x8 v1f = *(const bf16x8*)((const char*)VT + swz(32 + li5, cb));
        o0 = __builtin_amdgcn_mfma_f32_32x32x16_bf16(v0f, pf[kki], o0, 0, 0, 0);
        o1 = __builtin_amdgcn_mfma_f32_32x32x16_bf16(v1f, pf[kki], o1, 0, 0, 0);
        lsacc = __builtin_amdgcn_mfma_f32_32x32x16_bf16(ones, pf[kki], lsacc, 0, 0, 0);
      }
      __builtin_amdgcn_s_setprio(0);
    }

    // end-of-tile: drain this tile's prefetch, then block-wide barrier.
    asm volatile("s_waitcnt vmcnt(0)" ::: "memory");
    __builtin_amdgcn_s_barrier();
    __builtin_amdgcn_sched_barrier(0);
  }

  if (!partial) {
    // normalize + store. d = df*32 + 4*g2 + 8*r2 + rr
    const float inv = 1.f / lsacc[0];
    float* ob = Out + (((size_t)(b * 2048 + qg) * 8 + h) << 6);
#pragma unroll
    for (int r2 = 0; r2 < 4; ++r2) {
      const int doff = (g2 << 2) + (r2 << 3);
      float4 s0 = make_float4(o0[4 * r2] * inv, o0[4 * r2 + 1] * inv,
                              o0[4 * r2 + 2] * inv, o0[4 * r2 + 3] * inv);
      *(float4*)(ob + doff) = s0;
      float4 s1 = make_float4(o1[4 * r2] * inv, o1[4 * r2 + 1] * inv,
                              o1[4 * r2 + 2] * inv, o1[4 * r2 + 3] * inv);
      *(float4*)(ob + 32 + doff) = s1;
    }
  } else {
    // raw partial: bf16 O (unnormalized), fp32 (m2, lsum)
    const size_t pidx = ((size_t)bh * 8 + kk) * 128 + rloc;
    unsigned short* op = Opart + (size_t)slot * 2097152 + pidx * 64;
#pragma unroll
    for (int r2 = 0; r2 < 4; ++r2) {
      const int doff = (g2 << 2) + (r2 << 3);
      uint2 pa, pb;
      pa.x = cvtpk(o0[4 * r2], o0[4 * r2 + 1]);
      pa.y = cvtpk(o0[4 * r2 + 2], o0[4 * r2 + 3]);
      *(uint2*)(op + doff) = pa;
      pb.x = cvtpk(o1[4 * r2], o1[4 * r2 + 1]);
      pb.y = cvtpk(o1[4 * r2 + 2], o1[4 * r2 + 3]);
      *(uint2*)(op + 32 + doff) = pb;
    }
    float* mlp = Ml + ((size_t)slot * 32768 + pidx) * 2;
    mlp[0] = m2;
    mlp[1] = lsacc[0];
  }
}

// ---------------------------------------------------------------------------
// attn_combine: merge the two kv-half bf16 partials for q-tiles lt = 15-k.
// ---------------------------------------------------------------------------
__global__ __launch_bounds__(256) void attn_combine(
    const unsigned short* __restrict__ Opart, const float* __restrict__ Ml,
    float* __restrict__ Out) {
  const int tid = threadIdx.x;
  const int rowg = (int)blockIdx.x * 32 + (tid >> 3);
  const int d0 = (tid & 7) << 3;
  const int r = rowg & 127, kk = (rowg >> 7) & 7, bh = rowg >> 10;
  const int b = bh >> 3, h = bh & 7;
  const int lt = 15 - kk;
  const size_t pidx = (((size_t)bh * 8 + kk) * 128 + r);
  const size_t HOFF = 2097152;  // u16 per hf slot
  const size_t MOFF = 65536;    // floats per hf slot
  const float m0 = Ml[pidx * 2], ls0 = Ml[pidx * 2 + 1];
  const float m1 = Ml[MOFF + pidx * 2], ls1 = Ml[MOFF + pidx * 2 + 1];
  const float mm = fmaxf(m0, m1);
  const float w0 = exp2f(m0 - mm), w1 = exp2f(m1 - mm);
  const float inv = 1.f / (ls0 * w0 + ls1 * w1);
  const u16x8 A = *(const u16x8*)(Opart + pidx * 64 + d0);
  const u16x8 Bv = *(const u16x8*)(Opart + HOFF + pidx * 64 + d0);
  float res[8];
#pragma unroll
  for (int jj = 0; jj < 8; ++jj)
    res[jj] = (bf2f(A[jj]) * w0 + bf2f(Bv[jj]) * w1) * inv;
  const int qg = lt * 128 + r;
  float* o = Out + (((size_t)(b * 2048 + qg) * 8 + h) << 6) + d0;
  *(float4*)o = make_float4(res[0], res[1], res[2], res[3]);
  *(float4*)(o + 4) = make_float4(res[4], res[5], res[6], res[7]);
}

extern "C" void kernel_launch(void* const* d_in, const int* in_sizes, int n_in,
                              void* d_out, int out_size, void* d_ws, size_t ws_size,
                              hipStream_t stream) {
  const float* Q = (const float*)d_in[0];
  const float* K = (const float*)d_in[1];
  const float* V = (const float*)d_in[2];
  const float* M = (const float*)d_in[3];
  float* Out = (float*)d_out;
  char* ws = (char*)d_ws;
  const size_t MB = 1u << 20;
  unsigned short* Mth = (unsigned short*)(ws);            // [2048 t][2048 s]
  unsigned short* Mtl = (unsigned short*)(ws + 8 * MB);
  unsigned short* Kth = (unsigned short*)(ws + 16 * MB);  // [32 bh][64 e][2048 s]
  unsigned short* Ktl = (unsigned short*)(ws + 24 * MB);
  unsigned short* Vts = (unsigned short*)(ws + 32 * MB);  // [32 bh][64 d][2048 s]
  unsigned short* KMh = (unsigned short*)(ws + 40 * MB);  // [32 bh][2048 t][64 e]
  unsigned short* KMl = (unsigned short*)(ws + 48 * MB);
  // attn partials overlay the (dead after km) M staging regions:
  unsigned short* Opart = (unsigned short*)(ws);          // 2 x 4MB bf16
  float* Mlp = (float*)(ws + 8 * MB);                     // 512 KB fp32

  prep_all<<<dim3(32, 96), 256, 0, stream>>>(M, K, V, Mth, Mtl, Kth, Ktl, Vts);
  km_mfma<<<dim3(16, 32), 256, 0, stream>>>(Mth, Mtl, Kth, Ktl, KMh, KMl);
  attn32<<<dim3(768), 256, 0, stream>>>(Q, KMh, KMl, Vts, Out, Opart, Mlp);
  attn_combine<<<dim3(1024), 256, 0, stream>>>(Opart, Mlp, Out);
}